// Round 5
// baseline (149.161 us; speedup 1.0000x reference)
//
#include <hip/hip_runtime.h>

constexpr int HID  = 20;
constexpr int NEXP = 16;
constexpr int CAP  = 20480;       // per-expert list capacity (avg ~16.4k, +25% margin)
constexpr int SPB  = 512;         // samples per eval block (256 thr x 2)
constexpr int BPE  = CAP / SPB;   // 40 eval blocks per expert
constexpr int ROUNDS = 4;         // samples per lane in bucket kernel
constexpr int GSTRIDE = 16;       // ints between gcnt counters -> one 64B line each

__device__ __forceinline__ float silu(float v) {
    float e = __expf(-v);
    return v * __builtin_amdgcn_rcpf(1.0f + e);
}

// region index per reference _region_mask: first cell lower bound inclusive,
// upper bounds inclusive, outside [-4,4] (or NaN) -> -1 (=> output 0)
__device__ __forceinline__ int cell_idx(float v) {
    if (!(v >= -4.0f))  return -1;   // also catches NaN
    if (v <= -0.674f)   return 0;
    if (v <= 0.0f)      return 1;
    if (v <= 0.674f)    return 2;
    if (v <= 4.0f)      return 3;
    return -1;
}

// ---------------- kernel 1: bucket samples into per-expert lists ----------------
// 256 blocks x 256 thr x 4 samples. One atomic per (block,expert), padded lines.
__global__ __launch_bounds__(256) void bucket_kernel(
    const float* __restrict__ x, int n_total,
    int* __restrict__ gcnt, int* __restrict__ lists,
    float* __restrict__ out)
{
    __shared__ int wcnt[4][NEXP];
    __shared__ int wbase[4][NEXP];

    const int tid  = threadIdx.x;
    const int lane = tid & 63;
    const int wv   = tid >> 6;
    const int base = blockIdx.x * (4 * ROUNDS * 64) + wv * (ROUNDS * 64);
    const unsigned long long lmask = (1ull << lane) - 1ull;
    const float2* x2 = reinterpret_cast<const float2*>(x);

    unsigned int epack = 0;          // 4 rounds x 8-bit expert id
    int cnt[NEXP];
    #pragma unroll
    for (int k = 0; k < NEXP; ++k) cnt[k] = 0;

    // phase A: classify + per-wave histogram (all array indices compile-time)
    #pragma unroll
    for (int r = 0; r < ROUNDS; ++r) {
        const int n = base + r * 64 + lane;
        int e = 17;                              // 17 = no sample
        if (n < n_total) {
            const float2 xv = x2[n];             // coalesced 8B/lane
            const int c = cell_idx(xv.x), rr = cell_idx(xv.y);
            e = ((c | rr) >= 0) ? (c * 4 + rr) : 16;   // 16 = out of range
        }
        epack |= (unsigned)e << (r * 8);
        #pragma unroll
        for (int k = 0; k < NEXP; ++k)
            cnt[k] += (int)__popcll(__ballot(e == k));   // wave-uniform
    }

    if (lane == 0) {
        #pragma unroll
        for (int k = 0; k < NEXP; ++k) wcnt[wv][k] = cnt[k];
    }
    __syncthreads();

    // one atomic per expert, 16 lanes in parallel, each on its own cache line
    if (tid < NEXP) {
        const int c0 = wcnt[0][tid], c1 = wcnt[1][tid],
                  c2 = wcnt[2][tid], c3 = wcnt[3][tid];
        const int tot = c0 + c1 + c2 + c3;
        int old = 0;
        if (tot) old = atomicAdd(&gcnt[tid * GSTRIDE], tot);
        wbase[0][tid] = old;
        wbase[1][tid] = old + c0;
        wbase[2][tid] = old + c0 + c1;
        wbase[3][tid] = old + c0 + c1 + c2;
    }
    __syncthreads();

    int wb[NEXP], roff[NEXP];
    #pragma unroll
    for (int k = 0; k < NEXP; ++k) { wb[k] = wbase[wv][k]; roff[k] = 0; }

    // phase B: stable ranks -> scatter sample indices
    #pragma unroll
    for (int r = 0; r < ROUNDS; ++r) {
        const int e = (int)((epack >> (r * 8)) & 0xFFu);
        const int n = base + r * 64 + lane;
        int slot = -1;
        #pragma unroll
        for (int k = 0; k < NEXP; ++k) {
            const unsigned long long m = __ballot(e == k);
            if (e == k) slot = wb[k] + roff[k] + (int)__popcll(m & lmask);
            roff[k] += (int)__popcll(m);
        }
        if (e < NEXP)     lists[e * CAP + slot] = n;
        else if (e == 16) out[n] = 0.0f;       // out-of-range -> masked sum = 0
    }
}

// ---------------- kernel 2: evaluate, one expert per block, 2 samples/thread ----
// weights are wave-uniform reads from read-only memory -> s_load, v_fmac v,s,v;
// each scalar weight fetch now feeds TWO independent FMA chains.
__device__ __forceinline__ void layer20g2(float (&h0)[HID], float (&h1)[HID],
                                          const float* __restrict__ Wm,
                                          const float* __restrict__ bv) {
    float a0[HID], a1[HID];
    #pragma unroll
    for (int j = 0; j < HID; ++j) { const float b = bv[j]; a0[j] = b; a1[j] = b; }
    #pragma unroll
    for (int k = 0; k < HID; ++k) {
        const float k0 = h0[k], k1 = h1[k];
        #pragma unroll
        for (int j = 0; j < HID; ++j) {
            const float w = Wm[k * HID + j];   // uniform -> SGPR, reused 2x
            a0[j] = fmaf(k0, w, a0[j]);
            a1[j] = fmaf(k1, w, a1[j]);
        }
    }
    #pragma unroll
    for (int j = 0; j < HID; ++j) { h0[j] = silu(a0[j]); h1[j] = silu(a1[j]); }
}

__global__ __launch_bounds__(256) void eval_kernel(
    const float* __restrict__ x,
    const float* __restrict__ W1, const float* __restrict__ b1,
    const float* __restrict__ W2, const float* __restrict__ b2,
    const float* __restrict__ W3, const float* __restrict__ b3,
    const float* __restrict__ W4, const float* __restrict__ b4,
    const float* __restrict__ W5, const float* __restrict__ b5,
    const int* __restrict__ gcnt, const int* __restrict__ lists,
    float* __restrict__ out)
{
    const int e     = blockIdx.x / BPE;           // SGPR-uniform expert id
    const int cbase = (blockIdx.x % BPE) * SPB;
    const int ce    = gcnt[e * GSTRIDE];          // scalar load
    if (cbase >= ce) return;                      // uniform early-exit

    const int  s0 = cbase + threadIdx.x;
    const int  s1 = s0 + 256;
    const bool a0v = s0 < ce;
    const bool a1v = s1 < ce;
    const int  i0 = lists[e * CAP + (a0v ? s0 : cbase)];
    const int  i1 = lists[e * CAP + (a1v ? s1 : cbase)];

    const float2 xv0 = reinterpret_cast<const float2*>(x)[i0];
    const float2 xv1 = reinterpret_cast<const float2*>(x)[i1];

    const float* w1 = W1 + e * (2 * HID);
    const float* v1 = b1 + e * HID;
    const float* w2 = W2 + e * (HID * HID);
    const float* v2 = b2 + e * HID;
    const float* w3 = W3 + e * (HID * HID);
    const float* v3 = b3 + e * HID;
    const float* w4 = W4 + e * (HID * HID);
    const float* v4 = b4 + e * HID;
    const float* w5 = W5 + e * HID;
    const float* v5 = b5 + e;

    float h0[HID], h1[HID];
    // layer 1: 2 -> 20
    #pragma unroll
    for (int j = 0; j < HID; ++j) {
        const float wa = w1[j], wb = w1[HID + j], bb = v1[j];
        h0[j] = silu(fmaf(xv0.x, wa, fmaf(xv0.y, wb, bb)));
        h1[j] = silu(fmaf(xv1.x, wa, fmaf(xv1.y, wb, bb)));
    }
    // layers 2..4: 20 -> 20
    layer20g2(h0, h1, w2, v2);
    layer20g2(h0, h1, w3, v3);
    layer20g2(h0, h1, w4, v4);
    // layer 5: 20 -> 1
    float acc0 = v5[0], acc1 = acc0;
    #pragma unroll
    for (int k = 0; k < HID; ++k) {
        const float w = w5[k];
        acc0 = fmaf(h0[k], w, acc0);
        acc1 = fmaf(h1[k], w, acc1);
    }

    if (a0v) out[i0] = acc0;   // 4B scatter
    if (a1v) out[i1] = acc1;
}

extern "C" void kernel_launch(void* const* d_in, const int* in_sizes, int n_in,
                              void* d_out, int out_size, void* d_ws, size_t ws_size,
                              hipStream_t stream) {
    const float* x  = (const float*)d_in[0];
    const float* W1 = (const float*)d_in[1];
    const float* b1 = (const float*)d_in[2];
    const float* W2 = (const float*)d_in[3];
    const float* b2 = (const float*)d_in[4];
    const float* W3 = (const float*)d_in[5];
    const float* b3 = (const float*)d_in[6];
    const float* W4 = (const float*)d_in[7];
    const float* b4 = (const float*)d_in[8];
    const float* W5 = (const float*)d_in[9];
    const float* b5 = (const float*)d_in[10];
    float* out = (float*)d_out;

    const int n_total = in_sizes[0] / 2;          // 262144 samples

    int* gcnt  = (int*)d_ws;                      // 16 counters, 64B apart
    int* lists = (int*)d_ws + NEXP * GSTRIDE;     // 16 x CAP sample indices

    hipMemsetAsync(d_ws, 0, NEXP * GSTRIDE * sizeof(int), stream);

    const int k1_blocks = (n_total + (ROUNDS * 256) - 1) / (ROUNDS * 256); // 256
    hipLaunchKernelGGL(bucket_kernel, dim3(k1_blocks), dim3(256), 0, stream,
                       x, n_total, gcnt, lists, out);

    hipLaunchKernelGGL(eval_kernel, dim3(NEXP * BPE), dim3(256), 0, stream,
                       x, W1, b1, W2, b2, W3, b3, W4, b4, W5, b5,
                       gcnt, lists, out);
}